// Round 1
// baseline (165.408 us; speedup 1.0000x reference)
//
#include <hip/hip_runtime.h>

// Problem constants
#define N     4096
#define D     64
#define KF    128     // fused feature dim: [var+mu^2, -2mu] x [ivar, mu*ivar]
#define TK    32      // K-chunk staged in LDS
#define PITCH 68      // LDS row pitch (floats): 68*4=272B, 16B-aligned rows
#define DET_EPS 1e-8f

// Workspace layout (floats)
//   Ft : [KF][N]  = 524288
//   Gt : [KF][N]  = 524288
//   P  : [N]
//   S  : [N]
//   acc: [2]  (pos_sum_tri, neg_sum_tri)
#define WS_FT   0
#define WS_GT   (KF * N)
#define WS_P    (2 * KF * N)
#define WS_S    (2 * KF * N + N)
#define WS_ACC  (2 * KF * N + 2 * N)

// ---------------------------------------------------------------------------
// Kernel 1: per-row precompute.
// Block = 256 threads handles 64 rows (r0..r0+63).
//  Part A: P[r] = prod_d var, S[r] = sum_d mu^2/var  (wave shuffle reductions)
//  Part B: build transposed Ft/Gt via LDS transpose (coalesced both sides).
__global__ __launch_bounds__(256) void precompute_kernel(
    const float* __restrict__ mu, const float* __restrict__ var,
    float* __restrict__ Ft, float* __restrict__ Gt,
    float* __restrict__ P, float* __restrict__ S) {
  __shared__ float T[64][65];
  const int t = threadIdx.x;
  const int r0 = blockIdx.x * 64;
  const int lane = t & 63;
  const int wid = t >> 6;

  // Part A: one wave per row, 16 reps cover 64 rows.
  for (int rep = 0; rep < 16; ++rep) {
    const int r = r0 + rep * 4 + wid;
    const float v = var[r * D + lane];
    const float m = mu[r * D + lane];
    float prod = v;
    float ssum = m * m / v;
    #pragma unroll
    for (int off = 32; off > 0; off >>= 1) {
      prod *= __shfl_xor(prod, off);
      ssum += __shfl_xor(ssum, off);
    }
    if (lane == 0) { P[r] = prod; S[r] = ssum; }
  }

  // Part B: 4 transpose passes: pass0 -> Ft rows 0..63 (var+mu^2),
  // pass1 -> Ft rows 64..127 (-2mu), pass2 -> Gt 0..63 (1/var),
  // pass3 -> Gt 64..127 (mu/var).
  for (int pass = 0; pass < 4; ++pass) {
    __syncthreads();
    for (int rep = 0; rep < 16; ++rep) {
      const int linear = rep * 256 + t;
      const int m_ = linear >> 6;   // local row
      const int d_ = linear & 63;   // feature
      const int r = r0 + m_;
      const float v = var[r * D + d_];
      const float mm = mu[r * D + d_];
      float x;
      if (pass == 0)      x = v + mm * mm;
      else if (pass == 1) x = -2.0f * mm;
      else if (pass == 2) x = 1.0f / v;
      else                x = mm / v;
      T[m_][d_] = x;
    }
    __syncthreads();
    float* dst = (pass < 2) ? Ft : Gt;
    const int base = (pass & 1) * 64;
    for (int rep = 0; rep < 16; ++rep) {
      const int linear = rep * 256 + t;
      const int k = linear >> 6;    // feature index
      const int c = linear & 63;    // local row
      dst[(base + k) * N + r0 + c] = T[c][k];
    }
  }
}

// ---------------------------------------------------------------------------
// Kernel 2: upper-triangular pair tiles. Block = 256 threads, 64x64 tile.
// Each thread owns a 4x4 register tile, BOTH directions (S = F_i.G_j,
// T = F_j.G_i). K=128 chunked by 32 through LDS.
__global__ __launch_bounds__(256) void pair_kernel(
    const float* __restrict__ Ft, const float* __restrict__ Gt,
    const float* __restrict__ P, const float* __restrict__ S,
    const int* __restrict__ labels, float* __restrict__ acc) {
  const int it = blockIdx.x;
  const int jt = blockIdx.y;
  if (jt < it) return;   // upper triangle only (block-uniform)

  __shared__ float sFI[TK][PITCH];
  __shared__ float sGJ[TK][PITCH];
  __shared__ float sFJ[TK][PITCH];
  __shared__ float sGI[TK][PITCH];
  __shared__ float red[8];

  const int t = threadIdx.x;
  const int tx = t & 15;         // j-group
  const int ty = t >> 4;         // i-group
  const int i0 = it * 64;
  const int j0 = jt * 64;
  const int ty4 = ty * 4;
  const int tx4 = tx * 4;

  float Sacc[4][4] = {};
  float Tacc[4][4] = {};

  for (int k0 = 0; k0 < KF; k0 += TK) {
    __syncthreads();
    #pragma unroll
    for (int rep = 0; rep < 2; ++rep) {
      const int u = rep * 256 + t;
      const int k = u >> 4;
      const int q = (u & 15) << 2;
      const float4 fI = *(const float4*)&Ft[(k0 + k) * N + i0 + q];
      const float4 gJ = *(const float4*)&Gt[(k0 + k) * N + j0 + q];
      const float4 fJ = *(const float4*)&Ft[(k0 + k) * N + j0 + q];
      const float4 gI = *(const float4*)&Gt[(k0 + k) * N + i0 + q];
      *(float4*)&sFI[k][q] = fI;
      *(float4*)&sGJ[k][q] = gJ;
      *(float4*)&sFJ[k][q] = fJ;
      *(float4*)&sGI[k][q] = gI;
    }
    __syncthreads();
    #pragma unroll
    for (int k = 0; k < TK; ++k) {
      const float4 fi = *(const float4*)&sFI[k][ty4];
      const float4 gj = *(const float4*)&sGJ[k][tx4];
      const float4 fj = *(const float4*)&sFJ[k][tx4];
      const float4 gi = *(const float4*)&sGI[k][ty4];
      const float fia[4] = {fi.x, fi.y, fi.z, fi.w};
      const float gja[4] = {gj.x, gj.y, gj.z, gj.w};
      const float fja[4] = {fj.x, fj.y, fj.z, fj.w};
      const float gia[4] = {gi.x, gi.y, gi.z, gi.w};
      #pragma unroll
      for (int a = 0; a < 4; ++a) {
        #pragma unroll
        for (int b = 0; b < 4; ++b) {
          Sacc[a][b] += fia[a] * gja[b];   // M_ij
          Tacc[a][b] += gia[a] * fja[b];   // M_ji
        }
      }
    }
  }

  // Epilogue: sym-KL -> sigmoid -> masked accumulate (upper triangle only).
  float pi[4], si[4], pj[4], sj[4];
  int li[4], lj[4];
  #pragma unroll
  for (int a = 0; a < 4; ++a) {
    const int i = i0 + ty4 + a;
    pi[a] = P[i]; si[a] = S[i]; li[a] = labels[i];
  }
  #pragma unroll
  for (int b = 0; b < 4; ++b) {
    const int j = j0 + tx4 + b;
    pj[b] = P[j]; sj[b] = S[j]; lj[b] = labels[j];
  }

  float pos = 0.0f, neg = 0.0f;
  #pragma unroll
  for (int a = 0; a < 4; ++a) {
    #pragma unroll
    for (int b = 0; b < 4; ++b) {
      const int i = i0 + ty4 + a;
      const int j = j0 + tx4 + b;
      if (i < j) {
        const float det_ij = pj[b] / (pi[a] + DET_EPS);
        const float det_ji = pi[a] / (pj[b] + DET_EPS);
        const float sym = 0.25f * (Sacc[a][b] + Tacc[a][b] + si[a] + sj[b]
                                   + det_ij + det_ji - 2.0f * (float)D);
        const float val = 1.0f / (1.0f + __expf(-sym));
        if (li[a] == lj[b]) pos += val; else neg += val;
      }
    }
  }

  // Block reduction: wave shuffles then LDS, one atomic pair per block.
  #pragma unroll
  for (int off = 32; off > 0; off >>= 1) {
    pos += __shfl_down(pos, off);
    neg += __shfl_down(neg, off);
  }
  const int lane = t & 63, wid = t >> 6;
  if (lane == 0) { red[wid] = pos; red[4 + wid] = neg; }
  __syncthreads();
  if (t == 0) {
    atomicAdd(&acc[0], red[0] + red[1] + red[2] + red[3]);
    atomicAdd(&acc[1], red[4] + red[5] + red[6] + red[7]);
  }
}

// ---------------------------------------------------------------------------
// Kernel 3: finalize the 4 outputs. Full-grid sums = 2 * triangle sums.
__global__ void finalize_kernel(const float* __restrict__ acc,
                                float* __restrict__ out) {
  const float pos = 2.0f * acc[0];
  const float neg = 2.0f * acc[1];
  out[0] = pos * (1.0f / 16777216.0f);  // mean over N*N = 2^24
  out[1] = neg * (1.0f / 16777216.0f);
  out[2] = pos;
  out[3] = neg;
}

extern "C" void kernel_launch(void* const* d_in, const int* in_sizes, int n_in,
                              void* d_out, int out_size, void* d_ws, size_t ws_size,
                              hipStream_t stream) {
  const float* mu = (const float*)d_in[0];
  const float* var = (const float*)d_in[1];
  const int* labels = (const int*)d_in[2];
  float* out = (float*)d_out;
  float* ws = (float*)d_ws;

  float* Ft = ws + WS_FT;
  float* Gt = ws + WS_GT;
  float* P = ws + WS_P;
  float* S = ws + WS_S;
  float* acc = ws + WS_ACC;

  hipMemsetAsync(acc, 0, 2 * sizeof(float), stream);
  precompute_kernel<<<dim3(N / 64), dim3(256), 0, stream>>>(mu, var, Ft, Gt, P, S);
  pair_kernel<<<dim3(N / 64, N / 64), dim3(256), 0, stream>>>(Ft, Gt, P, S, labels, acc);
  finalize_kernel<<<dim3(1), dim3(1), 0, stream>>>(acc, out);
}

// Round 2
// 131.965 us; speedup vs baseline: 1.2534x; 1.2534x over previous
//
#include <hip/hip_runtime.h>

// Problem: N=4096 rows, D=64 feats, 10 classes.
// sym KL: sym_ij = 0.25*(H_i . H'_j + s_i + s_j + p_j/(p_i+eps) + p_i/(p_j+eps) - 128)
// where per-feature-d packed K layout (K=256):
//   H [r][4d+{0,1,2,3}] = { var+mu^2, -2mu, 1/var, mu/var }   (F0,F1,G0,G1)
//   H'[r][4d+{0,1,2,3}] = { 1/var, mu/var, var+mu^2, -2mu }   (G0,G1,F0,F1)
// so H_i . H'_j = F_i.G_j + G_i.F_j  (both KL directions in ONE K=256 dot).
// Outputs: mean/sum of sigmoid(sym) over same-label and diff-label off-diag pairs.

#define N 4096
#define D 64
#define KH 256
#define TILES 64           // 4096/64 tiles per side
#define NBLK 2080          // TILES*(TILES+1)/2 upper-tri blocks
#define DET_EPS 1e-8f

typedef short bf16x8 __attribute__((ext_vector_type(8)));
typedef float f32x16 __attribute__((ext_vector_type(16)));

// ws byte layout
#define WS_H    0                       // ushort[N][KH]   = 2 MB
#define WS_HP   (N * KH * 2)            // ushort[N][KH]   = 2 MB
#define WS_PSL  (2 * N * KH * 2)        // float4[N]       = 64 KB
#define WS_ACC  (WS_PSL + N * 16)       // float[2]

static __device__ __forceinline__ unsigned short f2bf(float x) {
  // round-to-nearest-even bf16
  unsigned int u = __float_as_uint(x);
  unsigned int r = (u + 0x7FFFu + ((u >> 16) & 1u)) >> 16;
  return (unsigned short)r;
}

// ---------------------------------------------------------------------------
// Kernel 1: per-row precompute. 1024 blocks x 256 thr; one wave per row.
__global__ __launch_bounds__(256) void precompute_kernel(
    const float* __restrict__ mu, const float* __restrict__ var,
    const int* __restrict__ labels,
    unsigned short* __restrict__ H, unsigned short* __restrict__ Hp,
    float4* __restrict__ PSL) {
  const int t = threadIdx.x;
  const int lane = t & 63;
  const int w = t >> 6;
  const int r = blockIdx.x * 4 + w;

  const float m = mu[r * D + lane];
  const float v = var[r * D + lane];
  const float g0 = 1.0f / v;
  const float f0 = v + m * m;
  const float f1 = -2.0f * m;
  const float g1 = m * g0;

  const ushort4 hf = make_ushort4(f2bf(f0), f2bf(f1), f2bf(g0), f2bf(g1));
  const ushort4 hg = make_ushort4(hf.z, hf.w, hf.x, hf.y);
  *(ushort4*)&H[r * KH + 4 * lane] = hf;   // 8B/lane, contiguous per wave
  *(ushort4*)&Hp[r * KH + 4 * lane] = hg;

  // wave reductions: p = prod var, s = sum mu^2/var
  float p = v;
  float s = m * m * g0;
  #pragma unroll
  for (int off = 1; off < 64; off <<= 1) {
    p *= __shfl_xor(p, off);
    s += __shfl_xor(s, off);
  }
  if (lane == 0) {
    PSL[r] = make_float4(p, 1.0f / (p + DET_EPS), s, (float)labels[r]);
  }
}

// ---------------------------------------------------------------------------
// Kernel 2: upper-tri 64x64 pair tiles, 4 waves, one 32x32 MFMA subtile each.
__global__ __launch_bounds__(256, 4) void pair_kernel(
    const unsigned short* __restrict__ H, const unsigned short* __restrict__ Hp,
    const float4* __restrict__ PSL, float* __restrict__ acc) {
  __shared__ float4 sPi[64];
  __shared__ float4 sPj[64];
  __shared__ float red[8];

  // triangular decode: block L -> (it, jt), it <= jt
  int L = (int)blockIdx.x;
  int it = (int)(64.5f - sqrtf(64.5f * 64.5f - 2.0f * (float)L));
  while (it > 0 && L < it * 64 - it * (it - 1) / 2) --it;
  while (L >= (it + 1) * 64 - (it + 1) * it / 2) ++it;
  const int jt = it + (L - (it * 64 - it * (it - 1) / 2));
  const int i0 = it * 64, j0 = jt * 64;

  const int t = threadIdx.x;
  const int lane = t & 63;
  const int w = t >> 6;               // 0..3
  const int sr = w >> 1, sc = w & 1;  // 2x2 subtiles of 32x32

  // stage per-row stats {p, 1/(p+eps), s, label}
  if (t < 64) sPi[t] = PSL[i0 + t];
  else if (t < 128) sPj[t - 64] = PSL[j0 + t - 64];

  const int l31 = lane & 31;
  const int khalf = (lane >> 5) * 8;   // A/B frag: row = lane&31, k = (lane>>5)*8 + j
  const unsigned short* pa = H + (size_t)(i0 + sr * 32 + l31) * KH + khalf;
  const unsigned short* pb = Hp + (size_t)(j0 + sc * 32 + l31) * KH + khalf;

  f32x16 C = {};
  #pragma unroll
  for (int k = 0; k < 16; ++k) {
    const bf16x8 a = *(const bf16x8*)(pa + k * 16);
    const bf16x8 b = *(const bf16x8*)(pb + k * 16);
    C = __builtin_amdgcn_mfma_f32_32x32x16_bf16(a, b, C, 0, 0, 0);
  }

  __syncthreads();

  // epilogue: C/D layout col=lane&31, row=(r&3)+8*(r>>2)+4*(lane>>5)
  const int jloc = sc * 32 + l31;
  const int j = j0 + jloc;
  const float4 pj = sPj[jloc];
  const int rbase = 4 * (lane >> 5);
  float pos = 0.0f, neg = 0.0f;
  #pragma unroll
  for (int r = 0; r < 16; ++r) {
    const int row = (r & 3) + 8 * (r >> 2) + rbase;
    const int iloc = sr * 32 + row;
    const int i = i0 + iloc;
    if (i < j) {                       // strict upper triangle only
      const float4 pi = sPi[iloc];
      const float sym = 0.25f * (C[r] + pi.z + pj.z
                                 + pj.x * pi.y + pi.x * pj.y - 128.0f);
      const float sig = __builtin_amdgcn_rcpf(1.0f + __expf(-sym));
      if (pi.w == pj.w) pos += sig; else neg += sig;
    }
  }

  // wave reduce -> LDS -> one atomic pair per block
  #pragma unroll
  for (int off = 32; off > 0; off >>= 1) {
    pos += __shfl_down(pos, off);
    neg += __shfl_down(neg, off);
  }
  if (lane == 0) { red[w] = pos; red[4 + w] = neg; }
  __syncthreads();
  if (t == 0) {
    atomicAdd(&acc[0], red[0] + red[1] + red[2] + red[3]);
    atomicAdd(&acc[1], red[4] + red[5] + red[6] + red[7]);
  }
}

// ---------------------------------------------------------------------------
// Kernel 3: finalize. Full-grid sums = 2 * triangle sums (sym matrix, diag=0).
__global__ void finalize_kernel(const float* __restrict__ acc,
                                float* __restrict__ out) {
  const float pos = 2.0f * acc[0];
  const float neg = 2.0f * acc[1];
  out[0] = pos * (1.0f / 16777216.0f);  // mean over N*N = 2^24
  out[1] = neg * (1.0f / 16777216.0f);
  out[2] = pos;
  out[3] = neg;
}

extern "C" void kernel_launch(void* const* d_in, const int* in_sizes, int n_in,
                              void* d_out, int out_size, void* d_ws, size_t ws_size,
                              hipStream_t stream) {
  const float* mu = (const float*)d_in[0];
  const float* var = (const float*)d_in[1];
  const int* labels = (const int*)d_in[2];
  float* out = (float*)d_out;
  char* ws = (char*)d_ws;

  unsigned short* H = (unsigned short*)(ws + WS_H);
  unsigned short* Hp = (unsigned short*)(ws + WS_HP);
  float4* PSL = (float4*)(ws + WS_PSL);
  float* acc = (float*)(ws + WS_ACC);

  hipMemsetAsync(acc, 0, 2 * sizeof(float), stream);
  precompute_kernel<<<dim3(N / 4), dim3(256), 0, stream>>>(mu, var, labels, H, Hp, PSL);
  pair_kernel<<<dim3(NBLK), dim3(256), 0, stream>>>(H, Hp, PSL, acc);
  finalize_kernel<<<dim3(1), dim3(1), 0, stream>>>(acc, out);
}

// Round 3
// 102.300 us; speedup vs baseline: 1.6169x; 1.2900x over previous
//
#include <hip/hip_runtime.h>

// Problem: N=4096 rows, D=64 feats, 10 classes.
// sym KL: sym_ij = 0.25*(H_i . H'_j + s_i + s_j + p_j/(p_i+eps) + p_i/(p_j+eps) - 128)
// where per-feature-d packed K layout (K=256):
//   H [r][4d+{0,1,2,3}] = { var+mu^2, -2mu, 1/var, mu/var }   (F0,F1,G0,G1)
//   H'[r][4d+{0,1,2,3}] = { 1/var, mu/var, var+mu^2, -2mu }   (G0,G1,F0,F1)
// so H_i . H'_j = F_i.G_j + G_i.F_j  (both KL directions in ONE K=256 dot).
// Outputs: mean/sum of sigmoid(sym) over same-label and diff-label off-diag pairs.
//
// R3 change vs R2: 2080 blocks x 2 same-address device atomicAdds serialized
// cross-XCD (~70us floor, MfmaUtil 2%). Replaced with per-block slot stores +
// tree-reduce finalize; memset dispatch eliminated.

#define N 4096
#define D 64
#define KH 256
#define TILES 64           // 4096/64 tiles per side
#define NBLK 2080          // TILES*(TILES+1)/2 upper-tri blocks
#define DET_EPS 1e-8f

typedef short bf16x8 __attribute__((ext_vector_type(8)));
typedef float f32x16 __attribute__((ext_vector_type(16)));

// ws byte layout
#define WS_H    0                       // ushort[N][KH]   = 2 MB
#define WS_HP   (N * KH * 2)            // ushort[N][KH]   = 2 MB
#define WS_PSL  (2 * N * KH * 2)        // float4[N]       = 64 KB
#define WS_PART (WS_PSL + N * 16)       // float[2*NBLK]   = 16.6 KB

static __device__ __forceinline__ unsigned short f2bf(float x) {
  // round-to-nearest-even bf16
  unsigned int u = __float_as_uint(x);
  unsigned int r = (u + 0x7FFFu + ((u >> 16) & 1u)) >> 16;
  return (unsigned short)r;
}

// ---------------------------------------------------------------------------
// Kernel 1: per-row precompute. 1024 blocks x 256 thr; one wave per row.
__global__ __launch_bounds__(256) void precompute_kernel(
    const float* __restrict__ mu, const float* __restrict__ var,
    const int* __restrict__ labels,
    unsigned short* __restrict__ H, unsigned short* __restrict__ Hp,
    float4* __restrict__ PSL) {
  const int t = threadIdx.x;
  const int lane = t & 63;
  const int w = t >> 6;
  const int r = blockIdx.x * 4 + w;

  const float m = mu[r * D + lane];
  const float v = var[r * D + lane];
  const float g0 = 1.0f / v;
  const float f0 = v + m * m;
  const float f1 = -2.0f * m;
  const float g1 = m * g0;

  const ushort4 hf = make_ushort4(f2bf(f0), f2bf(f1), f2bf(g0), f2bf(g1));
  const ushort4 hg = make_ushort4(hf.z, hf.w, hf.x, hf.y);
  *(ushort4*)&H[r * KH + 4 * lane] = hf;   // 8B/lane, contiguous per wave
  *(ushort4*)&Hp[r * KH + 4 * lane] = hg;

  // wave reductions: p = prod var, s = sum mu^2/var
  float p = v;
  float s = m * m * g0;
  #pragma unroll
  for (int off = 1; off < 64; off <<= 1) {
    p *= __shfl_xor(p, off);
    s += __shfl_xor(s, off);
  }
  if (lane == 0) {
    PSL[r] = make_float4(p, 1.0f / (p + DET_EPS), s, (float)labels[r]);
  }
}

// ---------------------------------------------------------------------------
// Kernel 2: upper-tri 64x64 pair tiles, 4 waves, one 32x32 MFMA subtile each.
// Partial sums stored to private per-block slots (NO contended atomics).
__global__ __launch_bounds__(256, 4) void pair_kernel(
    const unsigned short* __restrict__ H, const unsigned short* __restrict__ Hp,
    const float4* __restrict__ PSL, float* __restrict__ partial) {
  __shared__ float4 sPi[64];
  __shared__ float4 sPj[64];
  __shared__ float red[8];

  // triangular decode: block L -> (it, jt), it <= jt
  int L = (int)blockIdx.x;
  int it = (int)(64.5f - sqrtf(64.5f * 64.5f - 2.0f * (float)L));
  while (it > 0 && L < it * 64 - it * (it - 1) / 2) --it;
  while (L >= (it + 1) * 64 - (it + 1) * it / 2) ++it;
  const int jt = it + (L - (it * 64 - it * (it - 1) / 2));
  const int i0 = it * 64, j0 = jt * 64;

  const int t = threadIdx.x;
  const int lane = t & 63;
  const int w = t >> 6;               // 0..3
  const int sr = w >> 1, sc = w & 1;  // 2x2 subtiles of 32x32

  // stage per-row stats {p, 1/(p+eps), s, label}
  if (t < 64) sPi[t] = PSL[i0 + t];
  else if (t < 128) sPj[t - 64] = PSL[j0 + t - 64];

  const int l31 = lane & 31;
  const int khalf = (lane >> 5) * 8;   // A/B frag: row = lane&31, k = (lane>>5)*8 + j
  const unsigned short* pa = H + (size_t)(i0 + sr * 32 + l31) * KH + khalf;
  const unsigned short* pb = Hp + (size_t)(j0 + sc * 32 + l31) * KH + khalf;

  f32x16 C = {};
  #pragma unroll
  for (int k = 0; k < 16; ++k) {
    const bf16x8 a = *(const bf16x8*)(pa + k * 16);
    const bf16x8 b = *(const bf16x8*)(pb + k * 16);
    C = __builtin_amdgcn_mfma_f32_32x32x16_bf16(a, b, C, 0, 0, 0);
  }

  __syncthreads();

  // epilogue: C/D layout col=lane&31, row=(r&3)+8*(r>>2)+4*(lane>>5)
  const int jloc = sc * 32 + l31;
  const int j = j0 + jloc;
  const float4 pj = sPj[jloc];
  const int rbase = 4 * (lane >> 5);
  float pos = 0.0f, neg = 0.0f;
  #pragma unroll
  for (int r = 0; r < 16; ++r) {
    const int row = (r & 3) + 8 * (r >> 2) + rbase;
    const int iloc = sr * 32 + row;
    const int i = i0 + iloc;
    if (i < j) {                       // strict upper triangle only
      const float4 pi = sPi[iloc];
      const float sym = 0.25f * (C[r] + pi.z + pj.z
                                 + pj.x * pi.y + pi.x * pj.y - 128.0f);
      const float sig = __builtin_amdgcn_rcpf(1.0f + __expf(-sym));
      if (pi.w == pj.w) pos += sig; else neg += sig;
    }
  }

  // wave reduce -> LDS -> per-block private slot store (no atomics)
  #pragma unroll
  for (int off = 32; off > 0; off >>= 1) {
    pos += __shfl_down(pos, off);
    neg += __shfl_down(neg, off);
  }
  if (lane == 0) { red[w] = pos; red[4 + w] = neg; }
  __syncthreads();
  if (t == 0) {
    partial[L]        = red[0] + red[1] + red[2] + red[3];
    partial[NBLK + L] = red[4] + red[5] + red[6] + red[7];
  }
}

// ---------------------------------------------------------------------------
// Kernel 3: reduce per-block slots, finalize 4 outputs.
// Full-grid sums = 2 * triangle sums (sym matrix, diag excluded).
__global__ __launch_bounds__(256) void finalize_kernel(
    const float* __restrict__ partial, float* __restrict__ out) {
  __shared__ float redp[4], redn[4];
  const int t = threadIdx.x;
  const int lane = t & 63, w = t >> 6;
  float p = 0.0f, n = 0.0f;
  for (int i = t; i < NBLK; i += 256) {
    p += partial[i];
    n += partial[NBLK + i];
  }
  #pragma unroll
  for (int off = 32; off > 0; off >>= 1) {
    p += __shfl_down(p, off);
    n += __shfl_down(n, off);
  }
  if (lane == 0) { redp[w] = p; redn[w] = n; }
  __syncthreads();
  if (t == 0) {
    const float pos = 2.0f * (redp[0] + redp[1] + redp[2] + redp[3]);
    const float neg = 2.0f * (redn[0] + redn[1] + redn[2] + redn[3]);
    out[0] = pos * (1.0f / 16777216.0f);  // mean over N*N = 2^24
    out[1] = neg * (1.0f / 16777216.0f);
    out[2] = pos;
    out[3] = neg;
  }
}

extern "C" void kernel_launch(void* const* d_in, const int* in_sizes, int n_in,
                              void* d_out, int out_size, void* d_ws, size_t ws_size,
                              hipStream_t stream) {
  const float* mu = (const float*)d_in[0];
  const float* var = (const float*)d_in[1];
  const int* labels = (const int*)d_in[2];
  float* out = (float*)d_out;
  char* ws = (char*)d_ws;

  unsigned short* H = (unsigned short*)(ws + WS_H);
  unsigned short* Hp = (unsigned short*)(ws + WS_HP);
  float4* PSL = (float4*)(ws + WS_PSL);
  float* partial = (float*)(ws + WS_PART);

  precompute_kernel<<<dim3(N / 4), dim3(256), 0, stream>>>(mu, var, labels, H, Hp, PSL);
  pair_kernel<<<dim3(NBLK), dim3(256), 0, stream>>>(H, Hp, PSL, partial);
  finalize_kernel<<<dim3(1), dim3(256), 0, stream>>>(partial, out);
}

// Round 4
// 80.843 us; speedup vs baseline: 2.0460x; 1.2654x over previous
//
#include <hip/hip_runtime.h>

// Problem: N=4096 rows, D=64 feats, 10 classes.
// sym KL: sym_ij = 0.25*(H_i . H'_j + s_i + s_j + p_j/(p_i+eps) + p_i/(p_j+eps) - 128)
// per-feature packed K layout (K=256):
//   H [r][4d+{0,1,2,3}] = { var+mu^2, -2mu, 1/var, mu/var }   (F0,F1,G0,G1)
//   H'[r][4d+{0,1,2,3}] = { 1/var, mu/var, var+mu^2, -2mu }   (G0,G1,F0,F1)
// so H_i . H'_j = F_i.G_j + G_i.F_j  (both KL directions in ONE K=256 dot).
//
// R4 change vs R3: pair_kernel's fragment loads were 512-B-strided (32 scatter
// segments per vmem instr -> TA-pipe serialization, ~40us). H/Hp are now stored
// by precompute in MFMA-FRAGMENT-MAJOR order:
//   Hf[tile=r>>5][k=e>>4][(r&31)*16 + (e&15)]   (ushorts)
// so each k-step fragment load is 64 lanes x 16 B = 1 KB contiguous.

#define N 4096
#define D 64
#define KH 256
#define TILES 64           // 4096/64 tiles per side
#define NBLK 2080          // TILES*(TILES+1)/2 upper-tri blocks
#define DET_EPS 1e-8f

typedef short bf16x8 __attribute__((ext_vector_type(8)));
typedef float f32x16 __attribute__((ext_vector_type(16)));

// ws byte layout
#define WS_H    0                       // ushort[N/32][16][512]  = 2 MB (frag-major)
#define WS_HP   (N * KH * 2)            // ushort, same layout    = 2 MB
#define WS_PSL  (2 * N * KH * 2)        // float4[N]              = 64 KB
#define WS_PART (WS_PSL + N * 16)       // float[2*NBLK]

static __device__ __forceinline__ unsigned short f2bf(float x) {
  // round-to-nearest-even bf16
  unsigned int u = __float_as_uint(x);
  unsigned int r = (u + 0x7FFFu + ((u >> 16) & 1u)) >> 16;
  return (unsigned short)r;
}

// ---------------------------------------------------------------------------
// Kernel 1: per-row precompute. 1024 blocks x 256 thr; one wave per row.
// Stores H/Hp in fragment-major order (see header comment).
__global__ __launch_bounds__(256) void precompute_kernel(
    const float* __restrict__ mu, const float* __restrict__ var,
    const int* __restrict__ labels,
    unsigned short* __restrict__ Hf, unsigned short* __restrict__ Hpf,
    float4* __restrict__ PSL) {
  const int t = threadIdx.x;
  const int lane = t & 63;   // feature d
  const int w = t >> 6;
  const int r = blockIdx.x * 4 + w;

  const float m = mu[r * D + lane];
  const float v = var[r * D + lane];
  const float g0 = 1.0f / v;
  const float f0 = v + m * m;
  const float f1 = -2.0f * m;
  const float g1 = m * g0;

  // element index e = 4*d + c; frag-major idx:
  //   (r>>5)*8192 + (e>>4)*512 + (r&31)*16 + (e&15)
  // for lane d: e>>4 = d>>2, e&15 = (d&3)*4 + c  -> 4 contiguous ushorts.
  const size_t base = (size_t)(r >> 5) * 8192 + (size_t)(lane >> 2) * 512
                      + (size_t)(r & 31) * 16 + (size_t)(lane & 3) * 4;
  const ushort4 hf = make_ushort4(f2bf(f0), f2bf(f1), f2bf(g0), f2bf(g1));
  const ushort4 hg = make_ushort4(hf.z, hf.w, hf.x, hf.y);
  *(ushort4*)&Hf[base] = hf;
  *(ushort4*)&Hpf[base] = hg;

  // wave reductions: p = prod var, s = sum mu^2/var
  float p = v;
  float s = m * m * g0;
  #pragma unroll
  for (int off = 1; off < 64; off <<= 1) {
    p *= __shfl_xor(p, off);
    s += __shfl_xor(s, off);
  }
  if (lane == 0) {
    PSL[r] = make_float4(p, 1.0f / (p + DET_EPS), s, (float)labels[r]);
  }
}

// ---------------------------------------------------------------------------
// Kernel 2: upper-tri 64x64 pair tiles, 4 waves, one 32x32 MFMA subtile each.
// Fragment loads are 1-KB-contiguous per wave (frag-major global layout).
// Partial sums stored to private per-block slots (NO contended atomics).
__global__ __launch_bounds__(256, 4) void pair_kernel(
    const unsigned short* __restrict__ Hf, const unsigned short* __restrict__ Hpf,
    const float4* __restrict__ PSL, float* __restrict__ partial) {
  __shared__ float4 sPi[64];
  __shared__ float4 sPj[64];
  __shared__ float red[8];

  // triangular decode: block L -> (it, jt), it <= jt
  int L = (int)blockIdx.x;
  int it = (int)(64.5f - sqrtf(64.5f * 64.5f - 2.0f * (float)L));
  while (it > 0 && L < it * 64 - it * (it - 1) / 2) --it;
  while (L >= (it + 1) * 64 - (it + 1) * it / 2) ++it;
  const int jt = it + (L - (it * 64 - it * (it - 1) / 2));
  const int i0 = it * 64, j0 = jt * 64;

  const int t = threadIdx.x;
  const int lane = t & 63;
  const int w = t >> 6;               // 0..3
  const int sr = w >> 1, sc = w & 1;  // 2x2 subtiles of 32x32

  // stage per-row stats {p, 1/(p+eps), s, label}
  if (t < 64) sPi[t] = PSL[i0 + t];
  else if (t < 128) sPj[t - 64] = PSL[j0 + t - 64];

  // frag-major: lane slot = (lane&31)*16 + (lane>>5)*8; k-stride = 512 ushorts
  const int slot = (lane & 31) * 16 + (lane >> 5) * 8;
  const unsigned short* pa = Hf + (size_t)(i0 / 32 + sr) * 8192 + slot;
  const unsigned short* pb = Hpf + (size_t)(j0 / 32 + sc) * 8192 + slot;

  f32x16 C = {};
  #pragma unroll
  for (int k = 0; k < 16; ++k) {
    const bf16x8 a = *(const bf16x8*)(pa + k * 512);
    const bf16x8 b = *(const bf16x8*)(pb + k * 512);
    C = __builtin_amdgcn_mfma_f32_32x32x16_bf16(a, b, C, 0, 0, 0);
  }

  __syncthreads();

  // epilogue: C/D layout col=lane&31, row=(r&3)+8*(r>>2)+4*(lane>>5)
  const int l31 = lane & 31;
  const int jloc = sc * 32 + l31;
  const int j = j0 + jloc;
  const float4 pj = sPj[jloc];
  const int rbase = 4 * (lane >> 5);
  float pos = 0.0f, neg = 0.0f;
  #pragma unroll
  for (int r = 0; r < 16; ++r) {
    const int row = (r & 3) + 8 * (r >> 2) + rbase;
    const int iloc = sr * 32 + row;
    const int i = i0 + iloc;
    if (i < j) {                       // strict upper triangle only
      const float4 pi = sPi[iloc];
      const float sym = 0.25f * (C[r] + pi.z + pj.z
                                 + pj.x * pi.y + pi.x * pj.y - 128.0f);
      const float sig = __builtin_amdgcn_rcpf(1.0f + __expf(-sym));
      if (pi.w == pj.w) pos += sig; else neg += sig;
    }
  }

  // wave reduce -> LDS -> per-block private slot store (no atomics)
  #pragma unroll
  for (int off = 32; off > 0; off >>= 1) {
    pos += __shfl_down(pos, off);
    neg += __shfl_down(neg, off);
  }
  if (lane == 0) { red[w] = pos; red[4 + w] = neg; }
  __syncthreads();
  if (t == 0) {
    partial[L]        = red[0] + red[1] + red[2] + red[3];
    partial[NBLK + L] = red[4] + red[5] + red[6] + red[7];
  }
}

// ---------------------------------------------------------------------------
// Kernel 3: reduce per-block slots, finalize 4 outputs.
// Full-grid sums = 2 * triangle sums (sym matrix, diag excluded).
__global__ __launch_bounds__(256) void finalize_kernel(
    const float* __restrict__ partial, float* __restrict__ out) {
  __shared__ float redp[4], redn[4];
  const int t = threadIdx.x;
  const int lane = t & 63, w = t >> 6;
  float p = 0.0f, n = 0.0f;
  for (int i = t; i < NBLK; i += 256) {
    p += partial[i];
    n += partial[NBLK + i];
  }
  #pragma unroll
  for (int off = 32; off > 0; off >>= 1) {
    p += __shfl_down(p, off);
    n += __shfl_down(n, off);
  }
  if (lane == 0) { redp[w] = p; redn[w] = n; }
  __syncthreads();
  if (t == 0) {
    const float pos = 2.0f * (redp[0] + redp[1] + redp[2] + redp[3]);
    const float neg = 2.0f * (redn[0] + redn[1] + redn[2] + redn[3]);
    out[0] = pos * (1.0f / 16777216.0f);  // mean over N*N = 2^24
    out[1] = neg * (1.0f / 16777216.0f);
    out[2] = pos;
    out[3] = neg;
  }
}

extern "C" void kernel_launch(void* const* d_in, const int* in_sizes, int n_in,
                              void* d_out, int out_size, void* d_ws, size_t ws_size,
                              hipStream_t stream) {
  const float* mu = (const float*)d_in[0];
  const float* var = (const float*)d_in[1];
  const int* labels = (const int*)d_in[2];
  float* out = (float*)d_out;
  char* ws = (char*)d_ws;

  unsigned short* Hf = (unsigned short*)(ws + WS_H);
  unsigned short* Hpf = (unsigned short*)(ws + WS_HP);
  float4* PSL = (float4*)(ws + WS_PSL);
  float* partial = (float*)(ws + WS_PART);

  precompute_kernel<<<dim3(N / 4), dim3(256), 0, stream>>>(mu, var, labels, Hf, Hpf, PSL);
  pair_kernel<<<dim3(NBLK), dim3(256), 0, stream>>>(Hf, Hpf, PSL, partial);
  finalize_kernel<<<dim3(1), dim3(256), 0, stream>>>(partial, out);
}

// Round 5
// 78.819 us; speedup vs baseline: 2.0986x; 1.0257x over previous
//
#include <hip/hip_runtime.h>

// Problem: N=4096 rows, D=64 feats, 10 classes.
// sym KL: sym_ij = 0.25*(H_i . Hp_j + s_i + s_j + det_ij + det_ji - 128)
// per-feature packed K layout (K=256):
//   H[r][4d+{0,1,2,3}] = { var+mu^2, -2mu, 1/var, mu/var }   (F0,F1,G0,G1)
// Hp (the {G0,G1,F0,F1} order) is NOT stored: Hp[e] = H[pi(e)] where pi swaps
// components c<->c+2 within each 4-group; pi is an involution, so
//   sum_e H_i[e]*Hp_j[e] = sum_e H_i[e]*H_j[pi(e)]
// and pi on a lane's 8-element fragment is a 32-bit register permutation
// [v1,v0,v3,v2] -- done in-register, no second array.
//
// Storage is MFMA-FRAGMENT-MAJOR: Hf[tile=r>>5][k=e>>4][(r&31)*16 + (e&15)]
// so each k-step fragment load is 64 lanes x 16 B = 1 KB contiguous.
//
// R5 vs R4: 128x128 pair blocks (2x reuse, 135 MB L2 traffic), Hp eliminated
// (2 MB working set, L2-resident per XCD), folded epilogue constants.

#define N 4096
#define D 64
#define KH 256
#define MT 128             // pair block tile side
#define TILES2 32          // 4096/128
#define NBLK2 528          // TILES2*(TILES2+1)/2 upper-tri blocks
#define DET_EPS 1e-8f

typedef short bf16x8 __attribute__((ext_vector_type(8)));
typedef float f32x16 __attribute__((ext_vector_type(16)));

// ws byte layout
#define WS_H    0                       // ushort[N/32][16][512] = 2 MB (frag-major)
#define WS_PSL  (N * KH * 2)            // float4[N] = 64 KB
#define WS_PART (WS_PSL + N * 16)       // float[2*NBLK2]

static __device__ __forceinline__ unsigned short f2bf(float x) {
  // round-to-nearest-even bf16
  unsigned int u = __float_as_uint(x);
  unsigned int r = (u + 0x7FFFu + ((u >> 16) & 1u)) >> 16;
  return (unsigned short)r;
}

static __device__ __forceinline__ f32x16 mfma_bf16(bf16x8 a, bf16x8 b, f32x16 c) {
  return __builtin_amdgcn_mfma_f32_32x32x16_bf16(a, b, c, 0, 0, 0);
}

// ---------------------------------------------------------------------------
// Kernel 1: per-row precompute. 1024 blocks x 256 thr; one wave per row.
// Stores Hf (frag-major) and PSL = {p, 1/(p+eps), 0.25*s-16, label}.
__global__ __launch_bounds__(256) void precompute_kernel(
    const float* __restrict__ mu, const float* __restrict__ var,
    const int* __restrict__ labels,
    unsigned short* __restrict__ Hf, float4* __restrict__ PSL) {
  const int t = threadIdx.x;
  const int lane = t & 63;   // feature d
  const int w = t >> 6;
  const int r = blockIdx.x * 4 + w;

  const float m = mu[r * D + lane];
  const float v = var[r * D + lane];
  const float g0 = 1.0f / v;
  const float f0 = v + m * m;
  const float f1 = -2.0f * m;
  const float g1 = m * g0;

  // element e = 4*d + c; frag-major idx:
  //   (r>>5)*8192 + (e>>4)*512 + (r&31)*16 + (e&15)
  // lane d writes e = 4d..4d+3 -> 4 contiguous ushorts.
  const size_t base = (size_t)(r >> 5) * 8192 + (size_t)(lane >> 2) * 512
                      + (size_t)(r & 31) * 16 + (size_t)(lane & 3) * 4;
  *(ushort4*)&Hf[base] = make_ushort4(f2bf(f0), f2bf(f1), f2bf(g0), f2bf(g1));

  // wave reductions: p = prod var, s = sum mu^2/var
  float p = v;
  float s = m * m * g0;
  #pragma unroll
  for (int off = 1; off < 64; off <<= 1) {
    p *= __shfl_xor(p, off);
    s += __shfl_xor(s, off);
  }
  if (lane == 0) {
    PSL[r] = make_float4(p, 1.0f / (p + DET_EPS), 0.25f * s - 16.0f,
                         (float)labels[r]);
  }
}

// ---------------------------------------------------------------------------
// Kernel 2: upper-tri 128x128 pair tiles. 4 waves; wave w = quadrant
// (sr=w>>1, sc=w&1), each wave computes a 2x2 grid of 32x32 MFMA subtiles.
// B fragments derived from H via in-register component swap (see header).
__global__ __launch_bounds__(256, 2) void pair_kernel(
    const unsigned short* __restrict__ Hf,
    const float4* __restrict__ PSL, float* __restrict__ partial) {
  __shared__ float4 sPi[128];
  __shared__ float4 sPj[128];
  __shared__ float red[8];

  // triangular decode: block L -> (it, jt), it <= jt  (32x32 tile grid)
  int L = (int)blockIdx.x;
  int it = (int)(32.5f - sqrtf(32.5f * 32.5f - 2.0f * (float)L));
  while (it > 0 && L < it * TILES2 - it * (it - 1) / 2) --it;
  while (L >= (it + 1) * TILES2 - (it + 1) * it / 2) ++it;
  const int jt = it + (L - (it * TILES2 - it * (it - 1) / 2));
  const int i0 = it * MT, j0 = jt * MT;

  const int t = threadIdx.x;
  const int lane = t & 63;
  const int w = t >> 6;               // 0..3
  const int sr = w >> 1, sc = w & 1;  // 64x64 quadrant of the 128x128 block

  // stage per-row stats {p, 1/(p+eps), 0.25*s-16, label}
  if (t < 128) sPi[t] = PSL[i0 + t];
  else sPj[t - 128] = PSL[j0 + t - 128];
  __syncthreads();

  const int l31 = lane & 31;
  const int slot = l31 * 16 + (lane >> 5) * 8;  // frag-major lane slot
  const unsigned short* pa = Hf + (size_t)(i0 / 32 + sr * 2) * 8192 + slot;
  const unsigned short* pb = Hf + (size_t)(j0 / 32 + sc * 2) * 8192 + slot;

  // diagonal big-tile: quadrant (1,0) is entirely below the diagonal
  const bool active = !(it == jt && w == 2);

  f32x16 C00 = {}, C01 = {}, C10 = {}, C11 = {};
  float pos = 0.0f, neg = 0.0f;

  if (active) {
    #pragma unroll 4
    for (int k = 0; k < 16; ++k) {
      const bf16x8 a0 = *(const bf16x8*)(pa + k * 512);
      const bf16x8 a1 = *(const bf16x8*)(pa + 8192 + k * 512);
      const bf16x8 c0 = *(const bf16x8*)(pb + k * 512);
      const bf16x8 c1 = *(const bf16x8*)(pb + 8192 + k * 512);
      // pi(e): swap component pairs -> 32-bit reg perm [v1,v0,v3,v2]
      const bf16x8 b0 = __builtin_shufflevector(c0, c0, 2, 3, 0, 1, 6, 7, 4, 5);
      const bf16x8 b1 = __builtin_shufflevector(c1, c1, 2, 3, 0, 1, 6, 7, 4, 5);
      C00 = mfma_bf16(a0, b0, C00);
      C01 = mfma_bf16(a0, b1, C01);
      C10 = mfma_bf16(a1, b0, C10);
      C11 = mfma_bf16(a1, b1, C11);
    }

    // epilogue: C/D layout col=lane&31, row=(r&3)+8*(r>>2)+4*(lane>>5)
    const int rbase = 4 * (lane >> 5);
    #pragma unroll
    for (int mn = 0; mn < 4; ++mn) {
      const int m = mn >> 1, n = mn & 1;
      const f32x16 C = (mn == 0) ? C00 : (mn == 1) ? C01 : (mn == 2) ? C10 : C11;
      const int jloc = (sc * 2 + n) * 32 + l31;
      const int j = j0 + jloc;
      const float4 pj = sPj[jloc];
      #pragma unroll
      for (int r = 0; r < 16; ++r) {
        const int row = (r & 3) + 8 * (r >> 2) + rbase;
        const int iloc = (sr * 2 + m) * 32 + row;
        const int i = i0 + iloc;
        if (i < j) {                   // strict upper triangle only
          const float4 pi = sPi[iloc];
          const float det = pj.x * pi.y + pi.x * pj.y;
          const float sym = 0.25f * (C[r] + det) + pi.z + pj.z;
          const float sig = __builtin_amdgcn_rcpf(1.0f + __expf(-sym));
          if (pi.w == pj.w) pos += sig; else neg += sig;
        }
      }
    }
  }

  // wave reduce -> LDS -> per-block private slot store (no atomics)
  #pragma unroll
  for (int off = 32; off > 0; off >>= 1) {
    pos += __shfl_down(pos, off);
    neg += __shfl_down(neg, off);
  }
  if (lane == 0) { red[w] = pos; red[4 + w] = neg; }
  __syncthreads();
  if (t == 0) {
    partial[L]         = red[0] + red[1] + red[2] + red[3];
    partial[NBLK2 + L] = red[4] + red[5] + red[6] + red[7];
  }
}

// ---------------------------------------------------------------------------
// Kernel 3: reduce per-block slots, finalize 4 outputs.
// Full-grid sums = 2 * triangle sums (sym matrix, diag excluded).
__global__ __launch_bounds__(256) void finalize_kernel(
    const float* __restrict__ partial, float* __restrict__ out) {
  __shared__ float redp[4], redn[4];
  const int t = threadIdx.x;
  const int lane = t & 63, w = t >> 6;
  float p = 0.0f, n = 0.0f;
  for (int i = t; i < NBLK2; i += 256) {
    p += partial[i];
    n += partial[NBLK2 + i];
  }
  #pragma unroll
  for (int off = 32; off > 0; off >>= 1) {
    p += __shfl_down(p, off);
    n += __shfl_down(n, off);
  }
  if (lane == 0) { redp[w] = p; redn[w] = n; }
  __syncthreads();
  if (t == 0) {
    const float pos = 2.0f * (redp[0] + redp[1] + redp[2] + redp[3]);
    const float neg = 2.0f * (redn[0] + redn[1] + redn[2] + redn[3]);
    out[0] = pos * (1.0f / 16777216.0f);  // mean over N*N = 2^24
    out[1] = neg * (1.0f / 16777216.0f);
    out[2] = pos;
    out[3] = neg;
  }
}

extern "C" void kernel_launch(void* const* d_in, const int* in_sizes, int n_in,
                              void* d_out, int out_size, void* d_ws, size_t ws_size,
                              hipStream_t stream) {
  const float* mu = (const float*)d_in[0];
  const float* var = (const float*)d_in[1];
  const int* labels = (const int*)d_in[2];
  float* out = (float*)d_out;
  char* ws = (char*)d_ws;

  unsigned short* Hf = (unsigned short*)(ws + WS_H);
  float4* PSL = (float4*)(ws + WS_PSL);
  float* partial = (float*)(ws + WS_PART);

  precompute_kernel<<<dim3(N / 4), dim3(256), 0, stream>>>(mu, var, labels, Hf, PSL);
  pair_kernel<<<dim3(NBLK2), dim3(256), 0, stream>>>(Hf, PSL, partial);
  finalize_kernel<<<dim3(1), dim3(256), 0, stream>>>(partial, out);
}